// Round 5
// baseline (56.836 us; speedup 1.0000x reference)
//
#include <hip/hip_runtime.h>

#define BATCH 32
#define NN 116
#define EE 1346
#define HH 64
#define SPLITS 8
#define ECH 170        // K per split: 8*170 = 1360 >= 1346
#define PROW 128       // partial-buffer row stride
#define MBLK (SPLITS * BATCH)          // 256 mult1 blocks
#define HROWS 4
#define HBLK ((BATCH * NN) / HROWS)    // 232 hvw blocks

typedef __attribute__((ext_vector_type(8))) short bf16x8;
typedef __attribute__((ext_vector_type(4))) float f32x4;

__device__ __forceinline__ unsigned int pack_bf16(float a, float b) {
    union { float f; unsigned int u; } ua, ub;
    ua.f = a; ub.f = b;
    unsigned int lo = (ua.u + 0x7FFFu + ((ua.u >> 16) & 1u)) >> 16;
    unsigned int hi = (ub.u + 0x7FFFu + ((ub.u >> 16) & 1u)) >> 16;
    return lo | (hi << 16);
}

// ================= K1: mult1 partials (MFMA, pipelined) + HvW GEMV + out init =================
__global__ __launch_bounds__(256) void stage1_kernel(
    const float* __restrict__ T, const float* __restrict__ He,
    const float* __restrict__ pv,
    const float* __restrict__ Hv, const float* __restrict__ Wv,
    const float* __restrict__ bfc,
    float* __restrict__ part, float* __restrict__ HvW, float* __restrict__ out)
{
    const int blk = blockIdx.x;
    const int tid = threadIdx.x;

    __shared__ float del[192];
    __shared__ unsigned int Tt[2][128 * 16];    // [buf][row][32k] bf16, XOR-swizzled
    __shared__ unsigned int dTt[2][128 * 16];

    if (blk < MBLK) {
        // ---- mult1: part[s][b][n][m] = sum_{e in split s} T[n,e]*de[e]*T[m,e]
        const int s = blk & 7, b = blk >> 3;
        const int e0 = s * ECH;
        const int cnt = min(ECH, EE - e0);       // 170 or 156
        const int nsteps = (cnt + 31) >> 5;      // 6 or 5

        {
            const float p0 = pv[0], p1 = pv[1], p2 = pv[2], p3 = pv[3], p4 = pv[4];
            for (int i = tid; i < 192; i += 256) {
                float v = 0.f;
                if (i < cnt) {
                    const float* he = He + (size_t)(b * EE + e0 + i) * 5;
                    v = he[0]*p0 + he[1]*p1 + he[2]*p2 + he[3]*p3 + he[4]*p4;
                }
                del[i] = v;
            }
        }

        const int n  = tid >> 1;      // staging row
        const int hf = tid & 1;       // k half (16 floats)
        const float* src = T + ((size_t)b * NN + n) * EE + e0;

        float2 pfA[8], pfB[8];        // 2-deep prefetch: even chunks in A, odd in B
        auto pref = [&](int c, float2* pf) {
            const int kb = c * 32 + hf * 16;
            #pragma unroll
            for (int q = 0; q < 8; ++q) {
                float2 v = {0.f, 0.f};
                const int k = kb + q * 2;
                if (n < NN) {
                    if (k + 1 < cnt) v = *(const float2*)&src[k];
                    else if (k < cnt) v.x = src[k];
                }
                pf[q] = v;
            }
        };
        auto wlds = [&](int c, const float2* pf, int buf) {
            const int kb = c * 32 + hf * 16;
            #pragma unroll
            for (int q2 = 0; q2 < 2; ++q2) {
                uint4 tq, dq;
                unsigned int* tp = &tq.x;
                unsigned int* dp = &dq.x;
                #pragma unroll
                for (int j = 0; j < 4; ++j) {
                    const float2 v = pf[q2 * 4 + j];
                    const float2 d = *(const float2*)&del[kb + q2 * 8 + 2 * j];
                    tp[j] = pack_bf16(v.x, v.y);
                    dp[j] = pack_bf16(v.x * d.x, v.y * d.y);
                }
                const int byteoff = ((n * 64) + (hf * 32) + (q2 * 16)) ^ ((n & 7) << 4);
                *(uint4*)((char*)&Tt[buf][0]  + byteoff) = tq;
                *(uint4*)((char*)&dTt[buf][0] + byteoff) = dq;
            }
        };

        const int w = tid >> 6, lane = tid & 63;
        const int RO = (w >> 1) * 64, CO = (w & 1) * 64;
        const int rl = lane & 15, g = lane >> 4;

        f32x4 acc[4][4] = {};

        // prologue: chunks 0,1 in flight; write buf0; chunk 2 in flight
        pref(0, pfA);
        pref(1, pfB);
        __syncthreads();               // del ready
        wlds(0, pfA, 0);               // waits chunk 0
        if (2 < nsteps) pref(2, pfA);
        __syncthreads();               // buf0 visible

        for (int c = 0; c < nsteps; ++c) {
            const int buf = c & 1;
            // frag reads from current buffer
            bf16x8 af[4], bf[4];
            #pragma unroll
            for (int t = 0; t < 4; ++t) {
                const int ra = RO + t * 16 + rl;
                const int rb = CO + t * 16 + rl;
                af[t] = *(const bf16x8*)((const char*)&dTt[buf][0] + (((ra * 64) + g * 16) ^ ((ra & 7) << 4)));
                bf[t] = *(const bf16x8*)((const char*)&Tt[buf][0]  + (((rb * 64) + g * 16) ^ ((rb & 7) << 4)));
            }
            // stage next chunk into the other buffer; keep 2 chunks in flight
            if (c + 1 < nsteps) {
                float2* pf = ((c + 1) & 1) ? pfB : pfA;
                wlds(c + 1, pf, buf ^ 1);
                if (c + 3 < nsteps) pref(c + 3, pf);
            }
            // MFMA cluster (covers ds_write completion before the barrier)
            #pragma unroll
            for (int tn = 0; tn < 4; ++tn)
                #pragma unroll
                for (int tm = 0; tm < 4; ++tm)
                    acc[tn][tm] = __builtin_amdgcn_mfma_f32_16x16x32_bf16(
                        af[tn], bf[tm], acc[tn][tm], 0, 0, 0);
            __syncthreads();
        }

        // epilogue: f32 partial store (mult1 symmetric -> layout transposes harmless)
        float* pb = part + ((size_t)(s * BATCH + b) * NN) * PROW;
        #pragma unroll
        for (int tn = 0; tn < 4; ++tn) {
            #pragma unroll
            for (int r = 0; r < 4; ++r) {
                const int grow = RO + tn * 16 + g * 4 + r;
                if (grow >= NN) continue;
                float* rowp = pb + (size_t)grow * PROW + CO;
                #pragma unroll
                for (int tm = 0; tm < 4; ++tm)
                    rowp[tm * 16 + rl] = acc[tn][tm][r];
            }
        }
    } else if (blk < MBLK + HBLK) {
        // ---- HvW path: HvW[b,n,h] = sum_k Hv[b,n,k] * W_v[k,h]
        const int lin = (blk - MBLK) * HROWS + (tid >> 6);
        const int h   = tid & 63;
        const float* hv = Hv + (size_t)lin * NN;
        float acc = 0.f;
        #pragma unroll 4
        for (int k = 0; k < NN; ++k)
            acc = fmaf(hv[k], Wv[k * HH + h], acc);
        HvW[(size_t)lin * HH + h] = acc;
    } else {
        // ---- out init: out[b,o] = b_fc[o]
        if (tid < BATCH * 4) out[tid] = bfc[tid & 3];
    }
}

// ====== K2: Hv' = LReLU((Av .* fix_diag(sum_s part)) @ HvW + b_v); fused head ======
__global__ __launch_bounds__(256) void stage2_kernel(
    const float* __restrict__ part, const float* __restrict__ Av,
    const float* __restrict__ HvW, const float* __restrict__ bv,
    const float* __restrict__ Wfc, float* __restrict__ out)
{
    const int blk = blockIdx.x;              // 232 blocks x 4 rows (116/4=29: no b straddle)
    const int tid = threadIdx.x;
    const int lin0 = blk * 4;
    const int b  = lin0 / NN;
    const int n0 = lin0 - b * NN;

    __shared__ float adjs[4][128];
    __shared__ float xs[4][64];

    const size_t sstr = (size_t)BATCH * NN * PROW;
    #pragma unroll
    for (int it = 0; it < 2; ++it) {
        const int idx = tid + it * 256;
        const int r = idx >> 7, m = idx & 127;
        float v = 0.f;
        if (m < NN) {
            const size_t rowoff = ((size_t)b * NN + n0 + r) * PROW + m;
            float msum = 0.f;
            #pragma unroll
            for (int s = 0; s < SPLITS; ++s) msum += part[s * sstr + rowoff];
            const float a = Av[(size_t)(lin0 + r) * NN + m];
            v = a * ((m == n0 + r) ? 1.0f : msum);
        }
        adjs[r][m] = v;
    }
    __syncthreads();

    const int w = tid >> 6, h = tid & 63;
    const float* hw = HvW + (size_t)b * NN * HH + h;
    float acc = 0.f;
    #pragma unroll 4
    for (int m = 0; m < NN; ++m)
        acc = fmaf(adjs[w][m], hw[(size_t)m * HH], acc);
    float x = acc + bv[h];
    xs[w][h] = (x >= 0.f) ? x : 0.01f * x;   // LeakyReLU(0.01)
    __syncthreads();

    // head contribution: out[b,o] += (1/N) * sum_{r,h} xs[r][h] * Wfc[h,o]
    if (tid < 16) {
        const int r = tid >> 2, o = tid & 3;
        float a = 0.f;
        #pragma unroll 16
        for (int k = 0; k < HH; ++k)
            a = fmaf(xs[r][k], Wfc[k * 4 + o], a);
        atomicAdd(&out[b * 4 + o], a * (1.0f / NN));
    }
}

extern "C" void kernel_launch(void* const* d_in, const int* in_sizes, int n_in,
                              void* d_out, int out_size, void* d_ws, size_t ws_size,
                              hipStream_t stream) {
    const float* H_v   = (const float*)d_in[0];
    const float* H_e   = (const float*)d_in[1];
    const float* adj_v = (const float*)d_in[2];
    // d_in[3] = adj_e : dead for the returned output
    const float* T     = (const float*)d_in[4];
    const float* W_v   = (const float*)d_in[5];
    const float* p_v   = (const float*)d_in[6];
    const float* b_v   = (const float*)d_in[7];
    // d_in[8,9,10] = W_e, p_e, b_e : dead
    const float* W_fc  = (const float*)d_in[11];
    const float* b_fc  = (const float*)d_in[12];
    float* out = (float*)d_out;

    float* part = (float*)d_ws;                                   // [8][32][116][128] f32
    float* HvW  = part + (size_t)SPLITS * BATCH * NN * PROW;      // [32][116][64]

    stage1_kernel<<<MBLK + HBLK + 1, 256, 0, stream>>>(
        T, H_e, p_v, H_v, W_v, b_fc, part, HvW, out);
    stage2_kernel<<<HBLK, 256, 0, stream>>>(
        part, adj_v, HvW, b_v, W_fc, out);
}

// Round 7
// 55.899 us; speedup vs baseline: 1.0168x; 1.0168x over previous
//
#include <hip/hip_runtime.h>

#define BATCH 32
#define NN 116
#define EE 1346
#define HH 64
#define NCH 22      // ceil(1346/64) K-chunks

typedef __attribute__((ext_vector_type(8))) short bf16x8;
typedef __attribute__((ext_vector_type(4))) float f32x4;

__device__ __forceinline__ unsigned int pack_bf16(float a, float b) {
    union { float f; unsigned int u; } ua, ub;
    ua.f = a; ub.f = b;
    unsigned int lo = (ua.u + 0x7FFFu + ((ua.u >> 16) & 1u)) >> 16;
    unsigned int hi = (ub.u + 0x7FFFu + ((ub.u >> 16) & 1u)) >> 16;
    return lo | (hi << 16);
}
__device__ __forceinline__ unsigned short bf16_1(float a) {
    union { float f; unsigned int u; } ua; ua.f = a;
    return (unsigned short)((ua.u + 0x7FFFu + ((ua.u >> 16) & 1u)) >> 16);
}

// One block per (batch, row-half). Fully fused node layer:
//   P0: del = He.pv ; HvW = Hv@Wv (MFMA, bf16) -> HvWT resident in LDS
//   P1: mult1[half rows][all m] = sum_k T[n,k]*del[k]*T[m,k]  (MFMA, K=64 chunks)
//   P2: adjA = Av*(diag fix) -> bf16 ; Hv' = LReLU(adjA@HvW + bv) ; pool ; head partial
__global__ __launch_bounds__(512) void fused1_kernel(
    const float* __restrict__ T, const float* __restrict__ He,
    const float* __restrict__ pv, const float* __restrict__ Hv,
    const float* __restrict__ Wv, const float* __restrict__ Av,
    const float* __restrict__ bv, const float* __restrict__ Wfc,
    float* __restrict__ hp)
{
    const int blk  = blockIdx.x;
    const int b    = blk & 31;
    const int half = blk >> 5;
    const int tid  = threadIdx.x;
    const int w = tid >> 6, lane = tid & 63;
    const int rl = lane & 15, g = lane >> 4;

    __shared__ unsigned int X[8192];    // 32KB: Hv_lds bf16[128][128] -> Tt(16K)+dTt(8K) -> m1 f32[64][128]
    __shared__ unsigned int Cb[4096];   // 16KB: HvWT bf16 [h=64][m=128]
    __shared__ unsigned int Wb[4096];   // 16KB: WvT bf16 [h=64][k=128] -> adjA bf16 [r=64][m=128]
    __shared__ float del[1408];
    __shared__ float pooled[64];

    // frag loaders: LDS arrays stored [row][k] bf16, byte ^ ((row&7)<<4) swizzle
    auto frag256 = [&](const unsigned int* base, int row, int kkb) -> bf16x8 {
        return *(const bf16x8*)((const char*)base + ((row * 256 + kkb + g * 16) ^ ((row & 7) << 4)));
    };
    auto fragT = [&](const unsigned int* base, int row, int kkb) -> bf16x8 {
        return *(const bf16x8*)((const char*)base + ((row * 128 + kkb + g * 16) ^ ((row & 7) << 4)));
    };

    // ---------------- P0: del, Hv_lds, WvT, HvW ----------------
    {
        const float p0 = pv[0], p1 = pv[1], p2 = pv[2], p3 = pv[3], p4 = pv[4];
        for (int k = tid; k < 1408; k += 512) {
            float v = 0.f;
            if (k < EE) {
                const float* he = He + (size_t)(b * EE + k) * 5;
                v = he[0]*p0 + he[1]*p1 + he[2]*p2 + he[3]*p3 + he[4]*p4;
            }
            del[k] = v;
        }
        if (tid < 64) pooled[tid] = 0.f;
    }
    // Hv -> X bf16 [n=128][k=128]
    for (int idx = tid; idx < 128 * 64; idx += 512) {
        const int n = idx >> 6, kp = idx & 63;
        float2 v = {0.f, 0.f};
        if (n < NN && 2 * kp < NN) v = *(const float2*)&Hv[((size_t)b * NN + n) * NN + 2 * kp];
        *(unsigned int*)((char*)X + ((n * 256 + kp * 4) ^ ((n & 7) << 4))) = pack_bf16(v.x, v.y);
    }
    // WvT -> Wb bf16 [h=64][k=128]
    for (int idx = tid; idx < 64 * 64; idx += 512) {
        const int h = idx & 63, kp = idx >> 6;
        const int k = 2 * kp;
        float a = 0.f, c = 0.f;
        if (k < NN)     a = Wv[(size_t)k * HH + h];
        if (k + 1 < NN) c = Wv[(size_t)(k + 1) * HH + h];
        *(unsigned int*)((char*)Wb + ((h * 256 + kp * 4) ^ ((h & 7) << 4))) = pack_bf16(a, c);
    }
    __syncthreads();

    // HvW = Hv @ Wv : wave w -> rows w*16..+15, all 64 h. K=128.
    {
        f32x4 hacc[4] = {};
        #pragma unroll
        for (int kk = 0; kk < 4; ++kk) {
            const bf16x8 a = frag256(X, w * 16 + rl, kk * 64);
            #pragma unroll
            for (int ct = 0; ct < 4; ++ct) {
                const bf16x8 bb = frag256(Wb, ct * 16 + rl, kk * 64);
                hacc[ct] = __builtin_amdgcn_mfma_f32_16x16x32_bf16(a, bb, hacc[ct], 0, 0, 0);
            }
        }
        // scatter transposed: HvWT[h][n] bf16 into Cb
        #pragma unroll
        for (int ct = 0; ct < 4; ++ct) {
            #pragma unroll
            for (int r = 0; r < 4; ++r) {
                const int n  = w * 16 + g * 4 + r;
                const int h2 = ct * 16 + rl;
                *(unsigned short*)((char*)Cb + ((h2 * 256 + n * 2) ^ ((h2 & 7) << 4))) = bf16_1(hacc[ct][r]);
            }
        }
    }
    __syncthreads();   // X free for reuse; Cb complete

    // ---------------- P1: mult1 main loop ----------------
    unsigned int* Tt  = X;          // [128 rows][64k] bf16, 16KB
    unsigned int* dTt = X + 4096;   // [64 rows][64k] bf16, 8KB
    const int srow = tid >> 2;      // 0..127 staging row
    const int q    = tid & 3;       // 16-k quarter
    const float* Trow = T + ((size_t)b * NN + srow) * EE;
    const int arow = srow - half * 64;

    float2 pf[8];
    auto pref = [&](int c) {
        const int k0 = c * 64 + q * 16;
        #pragma unroll
        for (int j = 0; j < 8; ++j) {
            float2 v = {0.f, 0.f};
            const int k = k0 + 2 * j;
            if (srow < NN && k + 1 < EE) v = *(const float2*)&Trow[k];
            else if (srow < NN && k < EE) v.x = Trow[k];
            pf[j] = v;
        }
    };
    auto wlds = [&](int c) {
        const int k0 = c * 64 + q * 16;
        uint4 t0, t1;
        unsigned int* tp0 = &t0.x;
        unsigned int* tp1 = &t1.x;
        #pragma unroll
        for (int j = 0; j < 4; ++j) {
            tp0[j] = pack_bf16(pf[j].x, pf[j].y);
            tp1[j] = pack_bf16(pf[4 + j].x, pf[4 + j].y);
        }
        const int swz = (srow & 7) << 4;
        const int bo = srow * 128 + q * 32;
        *(uint4*)((char*)Tt + ((bo) ^ swz))      = t0;
        *(uint4*)((char*)Tt + ((bo + 16) ^ swz)) = t1;
        if (arow >= 0 && arow < 64) {
            uint4 d0, d1;
            unsigned int* dp0 = &d0.x;
            unsigned int* dp1 = &d1.x;
            #pragma unroll
            for (int j = 0; j < 4; ++j) {
                const float2 da = *(const float2*)&del[k0 + 2 * j];
                const float2 db = *(const float2*)&del[k0 + 8 + 2 * j];
                dp0[j] = pack_bf16(pf[j].x * da.x,     pf[j].y * da.y);
                dp1[j] = pack_bf16(pf[4 + j].x * db.x, pf[4 + j].y * db.y);
            }
            const int bo2 = arow * 128 + q * 32;
            *(uint4*)((char*)dTt + ((bo2) ^ swz))      = d0;
            *(uint4*)((char*)dTt + ((bo2 + 16) ^ swz)) = d1;
        }
    };

    // wave tiling: 2x4 -> each wave 32 rows x 32 cols (2x2 tiles)
    const int wr = w >> 2, wc = w & 3;
    f32x4 acc[2][2] = {};

    pref(0);
    for (int c = 0; c < NCH; ++c) {
        wlds(c);
        __syncthreads();
        if (c + 1 < NCH) pref(c + 1);
        #pragma unroll
        for (int kk = 0; kk < 2; ++kk) {
            bf16x8 af[2], bf[2];
            af[0] = fragT(dTt, wr * 32 + rl,      kk * 64);
            af[1] = fragT(dTt, wr * 32 + 16 + rl, kk * 64);
            bf[0] = fragT(Tt,  wc * 32 + rl,      kk * 64);
            bf[1] = fragT(Tt,  wc * 32 + 16 + rl, kk * 64);
            #pragma unroll
            for (int i = 0; i < 2; ++i)
                #pragma unroll
                for (int j = 0; j < 2; ++j)
                    acc[i][j] = __builtin_amdgcn_mfma_f32_16x16x32_bf16(
                        af[i], bf[j], acc[i][j], 0, 0, 0);
        }
        __syncthreads();
    }

    // ---------------- P2: epilogue ----------------
    // m1 f32 [64][128] into X
    float* m1 = (float*)X;
    #pragma unroll
    for (int i = 0; i < 2; ++i)
        #pragma unroll
        for (int j = 0; j < 2; ++j)
            #pragma unroll
            for (int r = 0; r < 4; ++r) {
                const int row = wr * 32 + i * 16 + g * 4 + r;
                const int col = wc * 32 + j * 16 + rl;
                m1[row * 128 + col] = acc[i][j][r];
            }
    __syncthreads();

    // adjA bf16 into Wb: adjA[r][m] = Av[n][m] * (m==n ? 1 : m1[r][m])
    for (int idx = tid; idx < 64 * 128; idx += 512) {
        const int r = idx >> 7, m = idx & 127;
        const int n = half * 64 + r;
        float a = 0.f;
        if (n < NN && m < NN) a = Av[((size_t)b * NN + n) * NN + m];
        const float v = a * ((m == n) ? 1.0f : m1[r * 128 + m]);
        *(unsigned short*)((char*)Wb + ((r * 256 + m * 2) ^ ((r & 7) << 4))) = bf16_1(v);
    }
    __syncthreads();

    // C2 = adjA @ HvW : 64 rows x 64 h. wave w: rows (w>>1)*16, cols (w&1)*32
    {
        const int wr2 = w >> 1, wc2 = w & 1;
        f32x4 c2[2] = {};
        #pragma unroll
        for (int kk = 0; kk < 4; ++kk) {
            const bf16x8 a = frag256(Wb, wr2 * 16 + rl, kk * 64);
            #pragma unroll
            for (int j = 0; j < 2; ++j) {
                const bf16x8 bb = frag256(Cb, wc2 * 32 + j * 16 + rl, kk * 64);
                c2[j] = __builtin_amdgcn_mfma_f32_16x16x32_bf16(a, bb, c2[j], 0, 0, 0);
            }
        }
        #pragma unroll
        for (int j = 0; j < 2; ++j) {
            const int h2 = wc2 * 32 + j * 16 + rl;
            const float bias = bv[h2];
            float s = 0.f;
            #pragma unroll
            for (int r = 0; r < 4; ++r) {
                const int n = half * 64 + wr2 * 16 + g * 4 + r;
                if (n < NN) {
                    const float x = c2[j][r] + bias;
                    s += (x >= 0.f) ? x : 0.01f * x;   // LeakyReLU(0.01)
                }
            }
            s += __shfl_xor(s, 16);
            s += __shfl_xor(s, 32);
            if (g == 0) atomicAdd(&pooled[h2], s);
        }
    }
    __syncthreads();

    // head partial: hp[blk][o] = sum_h pooled[h] * Wfc[h][o]
    if (tid < 4) {
        float p = 0.f;
        #pragma unroll 16
        for (int k = 0; k < HH; ++k)
            p = fmaf(pooled[k], Wfc[k * 4 + tid], p);
        hp[blk * 4 + tid] = p;
    }
}

// combine half partials: out[b,o] = bfc[o] + (hp[b] + hp[b+32]) / N
__global__ __launch_bounds__(128) void head2_kernel(
    const float* __restrict__ hp, const float* __restrict__ bfc,
    float* __restrict__ out)
{
    const int t = threadIdx.x;
    const int b = t >> 2, o = t & 3;
    out[t] = bfc[o] + (hp[b * 4 + o] + hp[(b + 32) * 4 + o]) * (1.0f / NN);
}

extern "C" void kernel_launch(void* const* d_in, const int* in_sizes, int n_in,
                              void* d_out, int out_size, void* d_ws, size_t ws_size,
                              hipStream_t stream) {
    const float* Hv  = (const float*)d_in[0];
    const float* He  = (const float*)d_in[1];
    const float* Av  = (const float*)d_in[2];
    // d_in[3] (adj_e) dead
    const float* T_  = (const float*)d_in[4];
    const float* Wv  = (const float*)d_in[5];
    const float* pv  = (const float*)d_in[6];
    const float* bv  = (const float*)d_in[7];
    // d_in[8,9,10] (W_e, p_e, b_e) dead
    const float* Wfc = (const float*)d_in[11];
    const float* bfc = (const float*)d_in[12];
    float* out = (float*)d_out;

    float* hp = (float*)d_ws;   // [64][4] head partials

    fused1_kernel<<<64, 512, 0, stream>>>(T_, He, pv, Hv, Wv, Av, bv, Wfc, hp);
    head2_kernel<<<1, 128, 0, stream>>>(hp, bfc, out);
}

// Round 8
// 47.491 us; speedup vs baseline: 1.1968x; 1.1770x over previous
//
#include <hip/hip_runtime.h>

#define BATCH 32
#define NN 116
#define EE 1346
#define HH 64
#define SPLITS 8
#define ECH 170        // K per split: 8*170 = 1360 >= 1346
#define MBLK 256       // mult1 blocks: 8 splits x 32 batches
#define HVBLK 116      // hvw blocks: 3712 rows / 32 per block
#define GRID (MBLK + HVBLK + 1)

typedef __attribute__((ext_vector_type(8))) short bf16x8;
typedef __attribute__((ext_vector_type(4))) float f32x4;

__device__ __forceinline__ unsigned int pack_bf16(float a, float b) {
    union { float f; unsigned int u; } ua, ub;
    ua.f = a; ub.f = b;
    unsigned int lo = (ua.u + 0x7FFFu + ((ua.u >> 16) & 1u)) >> 16;
    unsigned int hi = (ub.u + 0x7FFFu + ((ub.u >> 16) & 1u)) >> 16;
    return lo | (hi << 16);
}

// ===== K1: mult1 partials (MFMA, 512thr, K=64, 3 steps) + HvW GEMV + out init =====
__global__ __launch_bounds__(512) void stage1_kernel(
    const float* __restrict__ T, const float* __restrict__ He,
    const float* __restrict__ pv,
    const float* __restrict__ Hv, const float* __restrict__ Wv,
    const float* __restrict__ bfc,
    float* __restrict__ part, float* __restrict__ HvW, float* __restrict__ out)
{
    const int blk = blockIdx.x;
    const int tid = threadIdx.x;

    __shared__ float del[192];
    __shared__ unsigned int Tt[128 * 32];    // [row=128][64k] bf16, XOR-swizzled, 16KB
    __shared__ unsigned int dTt[128 * 32];   // de-scaled copy, 16KB

    if (blk < MBLK) {
        // ---- mult1: part[b][n][s][m] = sum_{e in split s} T[n,e]*de[e]*T[m,e]
        const int s = blk & 7, b = blk >> 3;
        const int e0 = s * ECH;
        const int cnt = min(ECH, EE - e0);        // 170 or 156
        const int nsteps = 3;                     // ceil(cnt/64)

        {
            const float p0 = pv[0], p1 = pv[1], p2 = pv[2], p3 = pv[3], p4 = pv[4];
            for (int i = tid; i < 192; i += 512) {
                float v = 0.f;
                if (i < cnt) {
                    const float* he = He + (size_t)(b * EE + e0 + i) * 5;
                    v = he[0]*p0 + he[1]*p1 + he[2]*p2 + he[3]*p3 + he[4]*p4;
                }
                del[i] = v;
            }
        }

        const int srow = tid >> 2;     // staging row 0..127
        const int q    = tid & 3;      // 16-k quarter of the 64-k chunk
        const float* Trow = T + ((size_t)b * NN + srow) * EE + e0;

        float2 pf[8];
        auto pref = [&](int c) {
            const int k0 = c * 64 + q * 16;
            #pragma unroll
            for (int j = 0; j < 8; ++j) {
                float2 v = {0.f, 0.f};
                const int k = k0 + 2 * j;
                if (srow < NN && k + 1 < cnt) v = *(const float2*)&Trow[k];
                else if (srow < NN && k < cnt) v.x = Trow[k];
                pf[j] = v;
            }
        };
        auto wlds = [&](int c) {
            const int k0 = c * 64 + q * 16;
            uint4 t0, t1, d0, d1;
            unsigned int* tp0 = &t0.x;  unsigned int* tp1 = &t1.x;
            unsigned int* dp0 = &d0.x;  unsigned int* dp1 = &d1.x;
            #pragma unroll
            for (int j = 0; j < 4; ++j) {
                const float2 va = pf[j];
                const float2 vb = pf[4 + j];
                const float2 da = *(const float2*)&del[k0 + 2 * j];
                const float2 db = *(const float2*)&del[k0 + 8 + 2 * j];
                tp0[j] = pack_bf16(va.x, va.y);
                tp1[j] = pack_bf16(vb.x, vb.y);
                dp0[j] = pack_bf16(va.x * da.x, va.y * da.y);
                dp1[j] = pack_bf16(vb.x * db.x, vb.y * db.y);
            }
            const int swz = (srow & 7) << 4;
            const int bo  = srow * 128 + q * 32;
            *(uint4*)((char*)Tt  + ((bo) ^ swz))      = t0;
            *(uint4*)((char*)Tt  + ((bo + 16) ^ swz)) = t1;
            *(uint4*)((char*)dTt + ((bo) ^ swz))      = d0;
            *(uint4*)((char*)dTt + ((bo + 16) ^ swz)) = d1;
        };

        // 8 waves as 2x4: wave tile = 64 rows x 32 cols
        const int w = tid >> 6, lane = tid & 63;
        const int wr = w >> 2, wc = w & 3;
        const int rl = lane & 15, g = lane >> 4;

        auto fragT = [&](const unsigned int* base, int row, int kkb) -> bf16x8 {
            return *(const bf16x8*)((const char*)base + ((row * 128 + kkb + g * 16) ^ ((row & 7) << 4)));
        };

        f32x4 acc[4][2] = {};

        pref(0);
        __syncthreads();               // del ready

        for (int c = 0; c < nsteps; ++c) {
            wlds(c);
            __syncthreads();           // tile visible
            if (c + 1 < nsteps) pref(c + 1);
            #pragma unroll
            for (int kk = 0; kk < 2; ++kk) {
                bf16x8 af[4], bf[2];
                #pragma unroll
                for (int i = 0; i < 4; ++i) af[i] = fragT(dTt, wr * 64 + i * 16 + rl, kk * 64);
                #pragma unroll
                for (int j = 0; j < 2; ++j) bf[j] = fragT(Tt,  wc * 32 + j * 16 + rl, kk * 64);
                #pragma unroll
                for (int tn = 0; tn < 4; ++tn)
                    #pragma unroll
                    for (int tm = 0; tm < 2; ++tm)
                        acc[tn][tm] = __builtin_amdgcn_mfma_f32_16x16x32_bf16(
                            af[tn], bf[tm], acc[tn][tm], 0, 0, 0);
            }
            __syncthreads();           // done reading before next overwrite
        }

        // epilogue: part[b][n][s][m]
        #pragma unroll
        for (int tn = 0; tn < 4; ++tn) {
            #pragma unroll
            for (int r = 0; r < 4; ++r) {
                const int grow = wr * 64 + tn * 16 + g * 4 + r;
                if (grow >= NN) continue;
                float* rowp = part + (((size_t)b * NN + grow) * SPLITS + s) * 128;
                #pragma unroll
                for (int tm = 0; tm < 2; ++tm)
                    rowp[wc * 32 + tm * 16 + rl] = acc[tn][tm][r];
            }
        }
    } else if (blk < MBLK + HVBLK) {
        // ---- HvW: 32 rows per block, 4 rows per wave (4-way ILP)
        const int l0 = (blk - MBLK) * 32 + (tid >> 6) * 4;
        const int h  = tid & 63;
        const float* hv0 = Hv + (size_t)(l0 + 0) * NN;
        const float* hv1 = Hv + (size_t)(l0 + 1) * NN;
        const float* hv2 = Hv + (size_t)(l0 + 2) * NN;
        const float* hv3 = Hv + (size_t)(l0 + 3) * NN;
        float a0 = 0.f, a1 = 0.f, a2 = 0.f, a3 = 0.f;
        #pragma unroll 4
        for (int k = 0; k < NN; ++k) {
            const float wv = Wv[k * HH + h];
            a0 = fmaf(hv0[k], wv, a0);
            a1 = fmaf(hv1[k], wv, a1);
            a2 = fmaf(hv2[k], wv, a2);
            a3 = fmaf(hv3[k], wv, a3);
        }
        HvW[(size_t)(l0 + 0) * HH + h] = a0;
        HvW[(size_t)(l0 + 1) * HH + h] = a1;
        HvW[(size_t)(l0 + 2) * HH + h] = a2;
        HvW[(size_t)(l0 + 3) * HH + h] = a3;
    } else {
        // ---- out init: out[b,o] = b_fc[o]
        if (tid < BATCH * 4) out[tid] = bfc[tid & 3];
    }
}

// ====== K2: Hv' = LReLU((Av .* fix_diag(sum_s part)) @ HvW + b_v); fused head ======
__global__ __launch_bounds__(256) void stage2_kernel(
    const float* __restrict__ part, const float* __restrict__ Av,
    const float* __restrict__ HvW, const float* __restrict__ bv,
    const float* __restrict__ Wfc, float* __restrict__ out)
{
    const int blk = blockIdx.x;              // 232 blocks x 4 rows (116/4=29: no b straddle)
    const int tid = threadIdx.x;
    const int lin0 = blk * 4;
    const int b  = lin0 / NN;
    const int n0 = lin0 - b * NN;

    __shared__ float adjs[4][128];
    __shared__ float xs[4][64];

    // adjA rows: contiguous 4KB-per-row partial-sum ([b][n][s][m] layout)
    #pragma unroll
    for (int it = 0; it < 2; ++it) {
        const int idx = tid + it * 256;
        const int r = idx >> 7, m = idx & 127;
        float v = 0.f;
        if (m < NN) {
            const float* pp = part + (((size_t)b * NN + n0 + r) * SPLITS) * 128 + m;
            float msum = 0.f;
            #pragma unroll
            for (int s2 = 0; s2 < SPLITS; ++s2) msum += pp[s2 * 128];
            const float a = Av[(size_t)(lin0 + r) * NN + m];
            v = a * ((m == n0 + r) ? 1.0f : msum);
        }
        adjs[r][m] = v;
    }
    __syncthreads();

    const int w = tid >> 6, h = tid & 63;
    const float* hw = HvW + (size_t)b * NN * HH + h;
    float acc = 0.f;
    #pragma unroll 4
    for (int m = 0; m < NN; ++m)
        acc = fmaf(adjs[w][m], hw[(size_t)m * HH], acc);
    float x = acc + bv[h];
    xs[w][h] = (x >= 0.f) ? x : 0.01f * x;   // LeakyReLU(0.01)
    __syncthreads();

    // fused head: out[b,o] += (1/N) * xs[r] . Wfc[:,o]
    if (tid < 16) {
        const int r = tid >> 2, o = tid & 3;
        float a = 0.f;
        #pragma unroll 16
        for (int k = 0; k < HH; ++k)
            a = fmaf(xs[r][k], Wfc[k * 4 + o], a);
        atomicAdd(&out[b * 4 + o], a * (1.0f / NN));
    }
}

extern "C" void kernel_launch(void* const* d_in, const int* in_sizes, int n_in,
                              void* d_out, int out_size, void* d_ws, size_t ws_size,
                              hipStream_t stream) {
    const float* Hv  = (const float*)d_in[0];
    const float* He  = (const float*)d_in[1];
    const float* Av  = (const float*)d_in[2];
    // d_in[3] (adj_e) dead
    const float* T_  = (const float*)d_in[4];
    const float* Wv  = (const float*)d_in[5];
    const float* pv  = (const float*)d_in[6];
    const float* bv  = (const float*)d_in[7];
    // d_in[8,9,10] (W_e, p_e, b_e) dead
    const float* Wfc = (const float*)d_in[11];
    const float* bfc = (const float*)d_in[12];
    float* out = (float*)d_out;

    float* part = (float*)d_ws;                                   // [32][116][8][128] f32
    float* HvW  = part + (size_t)BATCH * NN * SPLITS * 128;       // [32][116][64]

    stage1_kernel<<<GRID, 512, 0, stream>>>(
        T_, He, pv, Hv, Wv, bfc, part, HvW, out);
    stage2_kernel<<<(BATCH * NN) / 4, 256, 0, stream>>>(
        part, Av, HvW, bv, Wfc, out);
}

// Round 9
// 32.909 us; speedup vs baseline: 1.7271x; 1.4431x over previous
//
#include <hip/hip_runtime.h>

#define BATCH 32
#define NN 116
#define EE 1346
#define HH 64
#define SPLITS 8
#define ECH 170        // K per split: 8*170 = 1360 >= 1346
#define MBLK 256       // mult1 blocks: 8 splits x 32 batches
#define HVBLK 116      // hvw blocks: 3712 rows / 32 per block
#define GRID1 (MBLK + HVBLK + 1)

typedef __attribute__((ext_vector_type(8))) short bf16x8;
typedef __attribute__((ext_vector_type(4))) float f32x4;

__device__ __forceinline__ unsigned int pack_bf16(float a, float b) {
    union { float f; unsigned int u; } ua, ub;
    ua.f = a; ub.f = b;
    unsigned int lo = (ua.u + 0x7FFFu + ((ua.u >> 16) & 1u)) >> 16;
    unsigned int hi = (ub.u + 0x7FFFu + ((ub.u >> 16) & 1u)) >> 16;
    return lo | (hi << 16);
}
__device__ __forceinline__ unsigned short bf16_1(float a) {
    union { float f; unsigned int u; } ua; ua.f = a;
    return (unsigned short)((ua.u + 0x7FFFu + ((ua.u >> 16) & 1u)) >> 16);
}
__device__ __forceinline__ float bf2f(unsigned int bits16) {
    union { unsigned int u; float f; } x; x.u = bits16 << 16;
    return x.f;
}

// ===== K1: mult1 partials (MFMA, 512thr, K=64, 3 steps, bf16 out) + HvW GEMV + out init =====
__global__ __launch_bounds__(512) void stage1_kernel(
    const float* __restrict__ T, const float* __restrict__ He,
    const float* __restrict__ pv,
    const float* __restrict__ Hv, const float* __restrict__ Wv,
    const float* __restrict__ bfc,
    unsigned short* __restrict__ part16, float* __restrict__ HvW,
    float* __restrict__ out)
{
    const int blk = blockIdx.x;
    const int tid = threadIdx.x;

    __shared__ float del[192];
    __shared__ unsigned int Tt[128 * 32];    // [row=128][64k] bf16, XOR-swizzled, 16KB
    __shared__ unsigned int dTt[128 * 32];   // de-scaled copy, 16KB

    if (blk < MBLK) {
        // ---- mult1: part[b][n][s][m] = sum_{e in split s} T[n,e]*de[e]*T[m,e]
        const int s = blk & 7, b = blk >> 3;
        const int e0 = s * ECH;
        const int cnt = min(ECH, EE - e0);        // 170 or 156
        const int nsteps = 3;

        {
            const float p0 = pv[0], p1 = pv[1], p2 = pv[2], p3 = pv[3], p4 = pv[4];
            for (int i = tid; i < 192; i += 512) {
                float v = 0.f;
                if (i < cnt) {
                    const float* he = He + (size_t)(b * EE + e0 + i) * 5;
                    v = he[0]*p0 + he[1]*p1 + he[2]*p2 + he[3]*p3 + he[4]*p4;
                }
                del[i] = v;
            }
        }

        const int srow = tid >> 2;     // staging row 0..127
        const int q    = tid & 3;      // 16-k quarter of the 64-k chunk
        const float* Trow = T + ((size_t)b * NN + srow) * EE + e0;

        float2 pf[8];
        auto pref = [&](int c) {
            const int k0 = c * 64 + q * 16;
            #pragma unroll
            for (int j = 0; j < 8; ++j) {
                float2 v = {0.f, 0.f};
                const int k = k0 + 2 * j;
                if (srow < NN && k + 1 < cnt) v = *(const float2*)&Trow[k];
                else if (srow < NN && k < cnt) v.x = Trow[k];
                pf[j] = v;
            }
        };
        auto wlds = [&](int c) {
            const int k0 = c * 64 + q * 16;
            uint4 t0, t1, d0, d1;
            unsigned int* tp0 = &t0.x;  unsigned int* tp1 = &t1.x;
            unsigned int* dp0 = &d0.x;  unsigned int* dp1 = &d1.x;
            #pragma unroll
            for (int j = 0; j < 4; ++j) {
                const float2 va = pf[j];
                const float2 vb = pf[4 + j];
                const float2 da = *(const float2*)&del[k0 + 2 * j];
                const float2 db = *(const float2*)&del[k0 + 8 + 2 * j];
                tp0[j] = pack_bf16(va.x, va.y);
                tp1[j] = pack_bf16(vb.x, vb.y);
                dp0[j] = pack_bf16(va.x * da.x, va.y * da.y);
                dp1[j] = pack_bf16(vb.x * db.x, vb.y * db.y);
            }
            const int swz = (srow & 7) << 4;
            const int bo  = srow * 128 + q * 32;
            *(uint4*)((char*)Tt  + ((bo) ^ swz))      = t0;
            *(uint4*)((char*)Tt  + ((bo + 16) ^ swz)) = t1;
            *(uint4*)((char*)dTt + ((bo) ^ swz))      = d0;
            *(uint4*)((char*)dTt + ((bo + 16) ^ swz)) = d1;
        };

        const int w = tid >> 6, lane = tid & 63;
        const int wr = w >> 2, wc = w & 3;
        const int rl = lane & 15, g = lane >> 4;

        auto fragT = [&](const unsigned int* base, int row, int kkb) -> bf16x8 {
            return *(const bf16x8*)((const char*)base + ((row * 128 + kkb + g * 16) ^ ((row & 7) << 4)));
        };

        f32x4 acc[4][2] = {};

        pref(0);
        __syncthreads();               // del ready

        for (int c = 0; c < nsteps; ++c) {
            wlds(c);
            __syncthreads();           // tile visible
            if (c + 1 < nsteps) pref(c + 1);
            #pragma unroll
            for (int kk = 0; kk < 2; ++kk) {
                bf16x8 af[4], bf[2];
                #pragma unroll
                for (int i = 0; i < 4; ++i) af[i] = fragT(dTt, wr * 64 + i * 16 + rl, kk * 64);
                #pragma unroll
                for (int j = 0; j < 2; ++j) bf[j] = fragT(Tt,  wc * 32 + j * 16 + rl, kk * 64);
                #pragma unroll
                for (int tn = 0; tn < 4; ++tn)
                    #pragma unroll
                    for (int tm = 0; tm < 2; ++tm)
                        acc[tn][tm] = __builtin_amdgcn_mfma_f32_16x16x32_bf16(
                            af[tn], bf[tm], acc[tn][tm], 0, 0, 0);
            }
            __syncthreads();
        }

        // epilogue: bf16 partials, part16[b][n][s][m]
        #pragma unroll
        for (int tn = 0; tn < 4; ++tn) {
            #pragma unroll
            for (int r = 0; r < 4; ++r) {
                const int grow = wr * 64 + tn * 16 + g * 4 + r;
                if (grow >= NN) continue;
                unsigned short* rowp = part16 + (((size_t)b * NN + grow) * SPLITS + s) * 128;
                #pragma unroll
                for (int tm = 0; tm < 2; ++tm)
                    rowp[wc * 32 + tm * 16 + rl] = bf16_1(acc[tn][tm][r]);
            }
        }
    } else if (blk < MBLK + HVBLK) {
        // ---- HvW: 32 rows per block, 4 rows per wave (4-way ILP)
        const int l0 = (blk - MBLK) * 32 + (tid >> 6) * 4;
        const int h  = tid & 63;
        const float* hv0 = Hv + (size_t)(l0 + 0) * NN;
        const float* hv1 = Hv + (size_t)(l0 + 1) * NN;
        const float* hv2 = Hv + (size_t)(l0 + 2) * NN;
        const float* hv3 = Hv + (size_t)(l0 + 3) * NN;
        float a0 = 0.f, a1 = 0.f, a2 = 0.f, a3 = 0.f;
        #pragma unroll 4
        for (int k = 0; k < NN; ++k) {
            const float wv = Wv[k * HH + h];
            a0 = fmaf(hv0[k], wv, a0);
            a1 = fmaf(hv1[k], wv, a1);
            a2 = fmaf(hv2[k], wv, a2);
            a3 = fmaf(hv3[k], wv, a3);
        }
        HvW[(size_t)(l0 + 0) * HH + h] = a0;
        HvW[(size_t)(l0 + 1) * HH + h] = a1;
        HvW[(size_t)(l0 + 2) * HH + h] = a2;
        HvW[(size_t)(l0 + 3) * HH + h] = a3;
    } else {
        // ---- out init: out[b,o] = b_fc[o]
        if (tid < BATCH * 4) out[tid] = bfc[tid & 3];
    }
}

// ====== K2 (MFMA): per block = (b, 16-row slice). adjA build -> MFMA vs LDS HvWT
//        -> LeakyReLU -> slice-pool -> head partial atomics into bias-seeded out ======
__global__ __launch_bounds__(256) void stage2_kernel(
    const unsigned short* __restrict__ part16, const float* __restrict__ Av,
    const float* __restrict__ HvW, const float* __restrict__ bv,
    const float* __restrict__ Wfc, float* __restrict__ out)
{
    const int blk = blockIdx.x;          // 32 b x 8 slices
    const int b = blk >> 3;
    const int n0 = (blk & 7) * 16;
    const int tid = threadIdx.x;
    const int w = tid >> 6, lane = tid & 63;
    const int rl = lane & 15, g = lane >> 4;

    __shared__ unsigned int Cb[4096];    // HvWT bf16 [h=64][n=128], swizzled, 16KB
    __shared__ unsigned int Ab[1024];    // adjA bf16 [r=16][m=128], swizzled, 4KB
    __shared__ float sl[64];

    // HvWT staging (HvW[b] is L2-resident; 8 blocks share it)
    for (int idx = tid; idx < 64 * 64; idx += 256) {
        const int h = idx & 63, np = idx >> 6;
        const int n = 2 * np;
        const float v0 = (n < NN)     ? HvW[((size_t)b * NN + n) * HH + h]     : 0.f;
        const float v1 = (n + 1 < NN) ? HvW[((size_t)b * NN + n + 1) * HH + h] : 0.f;
        *(unsigned int*)((char*)Cb + ((h * 256 + np * 4) ^ ((h & 7) << 4))) = pack_bf16(v0, v1);
    }

    // adjA build: thread -> (r = tid>>4, 8 consecutive m at m0)
    {
        const int r = tid >> 4, m0 = (tid & 15) * 8;
        const int n = n0 + r;
        float ms[8] = {0.f,0.f,0.f,0.f,0.f,0.f,0.f,0.f};
        unsigned int outw[4];
        if (n < NN) {
            const unsigned short* pp = part16 + (((size_t)b * NN + n) * SPLITS) * 128 + m0;
            #pragma unroll
            for (int s = 0; s < SPLITS; ++s) {
                const uint4 u = *(const uint4*)(pp + (size_t)s * 128);
                const unsigned int* up = &u.x;
                #pragma unroll
                for (int j = 0; j < 4; ++j) {
                    ms[2*j]   += bf2f(up[j] & 0xffffu);
                    ms[2*j+1] += bf2f(up[j] >> 16);
                }
            }
            const float* avp = Av + ((size_t)b * NN + n) * NN;
            #pragma unroll
            for (int j = 0; j < 4; ++j) {
                const int m = m0 + 2 * j;
                const float a0 = (m < NN)     ? avp[m]     : 0.f;
                const float a1 = (m + 1 < NN) ? avp[m + 1] : 0.f;
                const float v0 = a0 * ((m     == n) ? 1.0f : ms[2*j]);
                const float v1 = a1 * ((m + 1 == n) ? 1.0f : ms[2*j+1]);
                outw[j] = pack_bf16(v0, v1);
            }
        } else {
            outw[0] = outw[1] = outw[2] = outw[3] = 0u;
        }
        *(uint4*)((char*)Ab + ((r * 256 + m0 * 2) ^ ((r & 7) << 4))) = *(uint4*)outw;
    }
    __syncthreads();

    // C2 tile = adjA(16 x 128) @ HvWT^T : wave w -> h-range w*16..+15
    f32x4 acc = {};
    #pragma unroll
    for (int kk = 0; kk < 4; ++kk) {
        const int hrow = w * 16 + rl;
        const bf16x8 a  = *(const bf16x8*)((const char*)Ab +
                          ((rl * 256 + kk * 64 + g * 16) ^ ((rl & 7) << 4)));
        const bf16x8 bb = *(const bf16x8*)((const char*)Cb +
                          ((hrow * 256 + kk * 64 + g * 16) ^ ((hrow & 7) << 4)));
        acc = __builtin_amdgcn_mfma_f32_16x16x32_bf16(a, bb, acc, 0, 0, 0);
    }
    // D[A-row = g*4+r][B-row(h) = w*16+rl]; LeakyReLU + pool over this slice's rows
    {
        const int h = w * 16 + rl;
        const float bias = bv[h];
        float s = 0.f;
        #pragma unroll
        for (int r = 0; r < 4; ++r) {
            const int n = n0 + g * 4 + r;
            if (n < NN) {
                const float x = acc[r] + bias;
                s += (x >= 0.f) ? x : 0.01f * x;   // LeakyReLU(0.01)
            }
        }
        s += __shfl_xor(s, 16);
        s += __shfl_xor(s, 32);
        if (g == 0) sl[h] = s;
    }
    __syncthreads();

    // head partial: out[b,o] += (1/N) * sl . Wfc[:,o]
    if (tid < 4) {
        float a = 0.f;
        #pragma unroll 16
        for (int k = 0; k < HH; ++k)
            a = fmaf(sl[k], Wfc[k * 4 + tid], a);
        atomicAdd(&out[b * 4 + tid], a * (1.0f / NN));
    }
}

extern "C" void kernel_launch(void* const* d_in, const int* in_sizes, int n_in,
                              void* d_out, int out_size, void* d_ws, size_t ws_size,
                              hipStream_t stream) {
    const float* Hv  = (const float*)d_in[0];
    const float* He  = (const float*)d_in[1];
    const float* Av  = (const float*)d_in[2];
    // d_in[3] (adj_e) dead
    const float* T_  = (const float*)d_in[4];
    const float* Wv  = (const float*)d_in[5];
    const float* pv  = (const float*)d_in[6];
    const float* bv  = (const float*)d_in[7];
    // d_in[8,9,10] (W_e, p_e, b_e) dead
    const float* Wfc = (const float*)d_in[11];
    const float* bfc = (const float*)d_in[12];
    float* out = (float*)d_out;

    unsigned short* part16 = (unsigned short*)d_ws;               // [32][116][8][128] bf16
    float* HvW = (float*)(part16 + (size_t)BATCH * NN * SPLITS * 128);  // [32][116][64] f32

    stage1_kernel<<<GRID1, 512, 0, stream>>>(
        T_, He, pv, Hv, Wv, bfc, part16, HvW, out);
    stage2_kernel<<<BATCH * 8, 256, 0, stream>>>(
        part16, Av, HvW, bv, Wfc, out);
}